// Round 4
// baseline (178.791 us; speedup 1.0000x reference)
//
#include <hip/hip_runtime.h>
#include <cstdint>

#define BB 4
#define CC 1024
#define DD 1024
#define HH 16
#define HD 64
#define NH3 3072

typedef __attribute__((ext_vector_type(8))) short short8;   // 8 x bf16 (4 VGPRs)
typedef __attribute__((ext_vector_type(4))) float f32x4;

#define MFMA16(a, b, c) __builtin_amdgcn_mfma_f32_16x16x32_bf16(a, b, c, 0, 0, 0)
#define EXP2 __builtin_amdgcn_exp2f

// async global->LDS, 16B per lane; LDS dest = uniform base + lane*16
__device__ __forceinline__ void glds16(const void* g, void* l) {
    __builtin_amdgcn_global_load_lds(
        (const __attribute__((address_space(1))) void*)g,
        (__attribute__((address_space(3))) void*)l, 16, 0, 0);
}

__device__ __forceinline__ ushort f2bf(float f) {
    union { float f; uint32_t u; } v; v.f = f;
    uint32_t r = v.u + 0x7FFF + ((v.u >> 16) & 1);   // round-to-nearest-even
    return (ushort)(r >> 16);
}

// pack two fp32 -> bf16x2 via v_perm_b32
__device__ __forceinline__ uint32_t pack2bf(float a, float b) {
    uint32_t ua = __float_as_uint(a), ub = __float_as_uint(b);
    ua += 0x7FFF + ((ua >> 16) & 1);
    ub += 0x7FFF + ((ub >> 16) & 1);
    return __builtin_amdgcn_perm(ua, ub, 0x03020706);  // lo16=bf(a), hi16=bf(b)
}

// ---------------------------------------------------------------------------
// prep: fused x->bf16 convert + w_qkv^T + w_proj^T (one launch)
// ---------------------------------------------------------------------------
__global__ __launch_bounds__(256)
void prep_kernel(const float* __restrict__ x, ushort* __restrict__ xbf,
                 const float* __restrict__ wqkv, ushort* __restrict__ wqkvT,
                 const float* __restrict__ wprj, ushort* __restrict__ wprjT)
{
    __shared__ float Ts[64 * 65];
    const int blk = blockIdx.x;
    const int t = threadIdx.x;

    if (blk < 4096) {
        int i = blk * 256 + t;
        float4 v = ((const float4*)x)[i];
        ushort4 o;
        o.x = f2bf(v.x); o.y = f2bf(v.y); o.z = f2bf(v.z); o.w = f2bf(v.w);
        ((ushort4*)xbf)[i] = o;
        return;
    }

    const float* in; ushort* outp; int K, N, n0, k0;
    if (blk < 4864) {
        int bx = blk - 4096;
        in = wqkv; outp = wqkvT; K = DD; N = NH3;
        n0 = (bx % 48) * 64; k0 = (bx / 48) * 64;
    } else {
        int bx = blk - 4864;
        in = wprj; outp = wprjT; K = DD; N = DD;
        n0 = (bx % 16) * 64; k0 = (bx / 16) * 64;
    }
    #pragma unroll
    for (int i = 0; i < 16; ++i) {
        int idx = t + i * 256;
        int r = idx >> 6, c = idx & 63;
        Ts[r * 65 + c] = in[(size_t)(k0 + r) * N + n0 + c];
    }
    __syncthreads();
    #pragma unroll
    for (int i = 0; i < 16; ++i) {
        int idx = t + i * 256;
        int rr = idx >> 6, cc = idx & 63;
        outp[(size_t)(n0 + rr) * K + k0 + cc] = f2bf(Ts[cc * 65 + rr]);
    }
}

// ---------------------------------------------------------------------------
// bf16 MFMA GEMM: MT x 128 tile, BK=32, 3-deep LDS ring + COUNTED vmcnt (T4).
// (unchanged from R3 -- attribution anchor)
// ---------------------------------------------------------------------------
template<int MODE, int MT>
__global__ __launch_bounds__(256)
void gemm_bt(const ushort* __restrict__ A, const ushort* __restrict__ Bt,
             const float* __restrict__ bias, float* __restrict__ Cf,
             ushort* __restrict__ qb, ushort* __restrict__ kb, ushort* __restrict__ vtb,
             int M, int N, int K)
{
    constexpr int MI = MT / 32;               // M-dir MFMA tiles per wave
    __shared__ ushort As[3][MT * 32];
    __shared__ ushort Bs[3][128 * 32];

    const int tid = threadIdx.x;
    const int wid = tid >> 6, lane = tid & 63;
    const int quad = lane >> 4, l15 = lane & 15;
    const int m0 = blockIdx.y * MT, n0 = blockIdx.x * 128;
    const int wm = (wid >> 1) * (MT / 2), wn = (wid & 1) * 64;

    const int sr = lane >> 2;
    const int sc = lane & 3;

    const int ar0 = wid * (MT / 4) + sr;
    const int acg0 = sc ^ ((ar0 >> 1) & 3);
    const int acg1 = sc ^ (((ar0 + 16) >> 1) & 3);
    const ushort* Ar0 = A + (size_t)(m0 + ar0) * K + acg0 * 8;
    const ushort* Ar1 = A + (size_t)(m0 + ar0 + 16) * K + acg1 * 8;   // MT=128 only
    const int br0 = wid * 32 + sr;
    const int bcg0 = sc ^ ((br0 >> 1) & 3);
    const int bcg1 = sc ^ (((br0 + 16) >> 1) & 3);
    const ushort* Br0 = Bt + (size_t)(n0 + br0) * K + bcg0 * 8;
    const ushort* Br1 = Bt + (size_t)(n0 + br0 + 16) * K + bcg1 * 8;

    f32x4 acc[MI][4];
    #pragma unroll
    for (int i = 0; i < MI; ++i)
        #pragma unroll
        for (int j = 0; j < 4; ++j) acc[i][j] = (f32x4)(0.0f);

#define GSTAGE(kn, bidx) do { \
        glds16(Ar0 + (kn), &As[bidx][(wid * (MT / 4)) * 32]); \
        glds16(Br0 + (kn), &Bs[bidx][(wid * 32) * 32]); \
        if (MT == 128) glds16(Ar1 + (kn), &As[bidx][(wid * 32 + 16) * 32]); \
        glds16(Br1 + (kn), &Bs[bidx][(wid * 32 + 16) * 32]); } while (0)

    GSTAGE(0, 0);
    GSTAGE(32, 1);

    int cur = 0;
    for (int k0 = 0; k0 < K; k0 += 32) {
        if (k0 + 32 < K) {
            if (MT == 128)
                asm volatile("s_waitcnt vmcnt(4)\n\ts_barrier" ::: "memory");
            else
                asm volatile("s_waitcnt vmcnt(3)\n\ts_barrier" ::: "memory");
        } else {
            asm volatile("s_waitcnt vmcnt(0)\n\ts_barrier" ::: "memory");
        }
        if (k0 + 64 < K) {
            const int nb = (cur >= 1) ? cur - 1 : 2;    // (cur+2) % 3
            GSTAGE(k0 + 64, nb);
        }

        short8 af[MI], bf[4];
        #pragma unroll
        for (int i = 0; i < MI; ++i) {
            int row = wm + i * 16 + l15;
            af[i] = *(const short8*)(&As[cur][row * 32 + (quad ^ ((row >> 1) & 3)) * 8]);
        }
        #pragma unroll
        for (int j = 0; j < 4; ++j) {
            int col = wn + j * 16 + l15;
            bf[j] = *(const short8*)(&Bs[cur][col * 32 + (quad ^ ((col >> 1) & 3)) * 8]);
        }
        #pragma unroll
        for (int i = 0; i < MI; ++i)
            #pragma unroll
            for (int j = 0; j < 4; ++j)
                acc[i][j] = MFMA16(af[i], bf[j], acc[i][j]);

        cur = (cur == 2) ? 0 : cur + 1;
    }
#undef GSTAGE

    if (MODE == 0) {
        #pragma unroll
        for (int i = 0; i < MI; ++i) {
            int row = m0 + wm + i * 16 + quad * 4;
            #pragma unroll
            for (int j = 0; j < 4; ++j) {
                int col = n0 + wn + j * 16 + l15;
                float bv = bias[col];
                #pragma unroll
                for (int r = 0; r < 4; ++r)
                    Cf[(size_t)(row + r) * N + col] = acc[i][j][r] + bv;
            }
        }
    } else {
        #pragma unroll
        for (int j = 0; j < 4; ++j) {
            int n = n0 + wn + j * 16 + l15;
            int three = n >> 10;
            int h = (n >> 6) & 15;
            int hd = n & 63;
            float scale = (three == 0) ? 0.1803368801f : 1.0f;  // 0.125*log2(e)
            float bv = bias[n];
            #pragma unroll
            for (int i = 0; i < MI; ++i) {
                int row = m0 + wm + i * 16 + quad * 4;
                #pragma unroll
                for (int r = 0; r < 4; ++r) {
                    int m = row + r;
                    int b = m >> 10, c = m & 1023;
                    ushort val = f2bf((acc[i][j][r] + bv) * scale);
                    if (three == 0)
                        qb[((size_t)((b * HH + h) * CC) + c) * HD + hd] = val;
                    else if (three == 1)
                        kb[((size_t)((b * HH + h) * CC) + c) * HD + hd] = val;
                    else
                        vtb[((size_t)((b * HH + h) * HD) + hd) * CC + c] = val;
                }
            }
        }
    }
}

// ---------------------------------------------------------------------------
// Flash attention v7: P kept IN REGISTERS (quad-shuffle layout transform
// replaces the LDS round-trip), K tri-buf + V quad-buf with 2-deep prefetch
// and COUNTED vmcnt(4) (never drains mid-loop), setprio around the PV MFMA
// cluster. LDS 56 KB (was 76).
//
// Layout transform (verified element-wise): S-phase leaves lane (quad,l15)
// holding P[qrow=l15][key=kb2*16+quad*4+r], packed pk[kb2][w]=bf16x2 of keys
// {sq*4+2w', sq*4+2w'+1}. PV A-operand needs P[qrow=l15][key=quad*8+j]:
//   word w of pf0 (keys<32):  src kb2 = quad>>1, sq=(quad&1)*2+(w>>1), word=w&1
//   word w of pf1 (keys>=32): src kb2 = 2+(quad>>1), same sq/word
// l15 preserved -> pure quad-permute -> __shfl(sq*16+l15) + cndmask on quad.
// ---------------------------------------------------------------------------
__device__ __forceinline__ short8 pvfrag(const uint32_t pk0[2], const uint32_t pk1[2],
                                         int quad, int l15) {
    union { short8 s; uint32_t u[4]; } r;
    #pragma unroll
    for (int w = 0; w < 4; ++w) {
        int src = ((quad & 1) * 2 + (w >> 1)) * 16 + l15;
        uint32_t v0 = (uint32_t)__shfl((int)pk0[w & 1], src);
        uint32_t v1 = (uint32_t)__shfl((int)pk1[w & 1], src);
        r.u[w] = (quad < 2) ? v0 : v1;
    }
    return r.s;
}

__global__ __launch_bounds__(256)
void attn_mfma7(const ushort* __restrict__ qb, const ushort* __restrict__ kb,
                const ushort* __restrict__ vt, ushort* __restrict__ attnb)
{
    __shared__ ushort lds[3 * 4096 + 4 * 4096];   // 56 KB: K tri-buf + V quad-buf
    const uint K0 = 0, K1 = 4096, K2 = 8192;
    const uint V0 = 12288, V1 = 16384, V2 = 20480, V3 = 24576;

    const int tid = threadIdx.x;
    const int wid = tid >> 6, lane = tid & 63;
    const int quad = lane >> 4, l15 = lane & 15;
    const int bh = blockIdx.x & 63;          // bh-fastest: XCD L2 locality
    const int qt = blockIdx.x >> 6;
    const int q0 = qt * 128;
    const int b = bh >> 4, h = bh & 15;

    const ushort* Qp  = qb + ((size_t)bh * CC + q0) * HD;
    const ushort* Kp  = kb + (size_t)bh * CC * HD;
    const ushort* Vtp = vt + (size_t)bh * HD * CC;

    const int sr = lane >> 3;    // 0..7
    const int sc = lane & 7;     // chunk 0..7

    // Q fragments straight from global: B-operand [n=qrow][k=d], kt-invariant
    short8 qf[2][2];
    #pragma unroll
    for (int q2 = 0; q2 < 2; ++q2) {
        int row = wid * 32 + q2 * 16 + l15;
        #pragma unroll
        for (int s = 0; s < 2; ++s)
            qf[q2][s] = *(const short8*)(Qp + (size_t)row * HD + (s * 4 + quad) * 8);
    }

    // staging addresses (kt-invariant parts)
    const int kr = wid * 16 + sr;            // rows kr, kr+8
    const int cgA = sc ^ (kr & 7);
    const int cgB = sc ^ ((kr + 8) & 7);
    const ushort* Kr0 = Kp  + (size_t)kr * HD + cgA * 8;
    const ushort* Kr1 = Kp  + (size_t)(kr + 8) * HD + cgB * 8;
    const ushort* Vr0 = Vtp + (size_t)kr * CC + cgA * 8;
    const ushort* Vr1 = Vtp + (size_t)(kr + 8) * CC + cgB * 8;

    const uint stg0 = (wid * 16) * 64;       // LDS staging offsets within a buffer
    const uint stg1 = (wid * 16 + 8) * 64;

    // prologue: stage tiles 0 and 1 (tile 0 first -- vmcnt counts oldest)
    glds16(Kr0, lds + K0 + stg0);
    glds16(Kr1, lds + K0 + stg1);
    glds16(Vr0, lds + V0 + stg0);
    glds16(Vr1, lds + V0 + stg1);
    glds16(Kr0 + (size_t)64 * HD, lds + K1 + stg0);
    glds16(Kr1 + (size_t)64 * HD, lds + K1 + stg1);
    glds16(Vr0 + 64, lds + V1 + stg0);
    glds16(Vr1 + 64, lds + V1 + stg1);

    f32x4 oacc[2][4];
    #pragma unroll
    for (int q2 = 0; q2 < 2; ++q2)
        #pragma unroll
        for (int hb = 0; hb < 4; ++hb) oacc[q2][hb] = (f32x4)(0.0f);
    float lsum[2] = {0.0f, 0.0f};

    uint ksC = K0, ksN = K1, ksF = K2;
    uint vsP = V3, vsC = V0, vsN = V1, vsF = V2;

    uint32_t pkA[2][4][2], pkB[2][4][2];
    #pragma unroll
    for (int q2 = 0; q2 < 2; ++q2)
        #pragma unroll
        for (int kb2 = 0; kb2 < 4; ++kb2)
            pkA[q2][kb2][0] = pkA[q2][kb2][1] = 0u;

    // PV of the PREVIOUS tile: O += P_prev @ V_prev (reads vsP + PKP regs)
#define APV(PKP) do { \
        short8 vf_[4][2]; \
        _Pragma("unroll") \
        for (int hb = 0; hb < 4; ++hb) { \
            int hr = hb * 16 + l15; \
            vf_[hb][0] = *(const short8*)(lds + vsP + hr * 64 + ((quad ^ (hr & 7)) * 8)); \
            vf_[hb][1] = *(const short8*)(lds + vsP + hr * 64 + (((4 + quad) ^ (hr & 7)) * 8)); \
        } \
        short8 pf_[2][2]; \
        _Pragma("unroll") \
        for (int q2 = 0; q2 < 2; ++q2) { \
            pf_[q2][0] = pvfrag(PKP[q2][0], PKP[q2][1], quad, l15); \
            pf_[q2][1] = pvfrag(PKP[q2][2], PKP[q2][3], quad, l15); \
        } \
        __builtin_amdgcn_s_setprio(1); \
        _Pragma("unroll") \
        for (int q2 = 0; q2 < 2; ++q2) \
            _Pragma("unroll") \
            for (int hb = 0; hb < 4; ++hb) { \
                oacc[q2][hb] = MFMA16(pf_[q2][0], vf_[hb][0], oacc[q2][hb]); \
                oacc[q2][hb] = MFMA16(pf_[q2][1], vf_[hb][1], oacc[q2][hb]); \
            } \
        __builtin_amdgcn_s_setprio(0); \
    } while (0)

#define AITER(kt, PKP, PKC) do { \
        if ((kt) < 15) asm volatile("s_waitcnt vmcnt(4)\n\ts_barrier" ::: "memory"); \
        else           asm volatile("s_waitcnt vmcnt(0)\n\ts_barrier" ::: "memory"); \
        if ((kt) < 14) {                     /* prefetch tile kt+2 (2-deep) */ \
            const int koff_ = ((kt) + 2) * 64; \
            glds16(Kr0 + (size_t)koff_ * HD, lds + ksF + stg0); \
            glds16(Kr1 + (size_t)koff_ * HD, lds + ksF + stg1); \
            glds16(Vr0 + koff_,              lds + vsF + stg0); \
            glds16(Vr1 + koff_,              lds + vsF + stg1); \
        } \
        if ((kt) > 0) APV(PKP); \
        /* S_kt = K @ Q^T : lane holds S[qrow=l15][key=kb2*16+quad*4+r] */ \
        _Pragma("unroll") \
        for (int kb2 = 0; kb2 < 4; ++kb2) { \
            int krow_ = kb2 * 16 + l15; \
            short8 kf0_ = *(const short8*)(lds + ksC + krow_ * 64 + ((quad ^ (krow_ & 7)) * 8)); \
            short8 kf1_ = *(const short8*)(lds + ksC + krow_ * 64 + (((4 + quad) ^ (krow_ & 7)) * 8)); \
            _Pragma("unroll") \
            for (int q2 = 0; q2 < 2; ++q2) { \
                f32x4 st_ = (f32x4)(0.0f); \
                st_ = MFMA16(kf0_, qf[q2][0], st_); \
                st_ = MFMA16(kf1_, qf[q2][1], st_); \
                float p0_ = EXP2(st_[0]); \
                float p1_ = EXP2(st_[1]); \
                float p2_ = EXP2(st_[2]); \
                float p3_ = EXP2(st_[3]); \
                lsum[q2] += (p0_ + p1_) + (p2_ + p3_); \
                PKC[q2][kb2][0] = pack2bf(p0_, p1_); \
                PKC[q2][kb2][1] = pack2bf(p2_, p3_); \
            } \
        } \
        /* rotate ring buffers */ \
        uint t_ = ksC; ksC = ksN; ksN = ksF; ksF = t_; \
        t_ = vsP; vsP = vsC; vsC = vsN; vsN = vsF; vsF = t_; \
    } while (0)

    for (int k2 = 0; k2 < 8; ++k2) {        // unroll-by-2: static pkA/pkB swap
        AITER(2 * k2,     pkA, pkB);
        AITER(2 * k2 + 1, pkB, pkA);
    }

    // final PV_15: P_15 in pkA, V_15 at vsP (post-rotation); no barrier needed
    APV(pkA);
#undef AITER
#undef APV

    // reduce lsum across the 4 quads (lanes sharing l15)
    #pragma unroll
    for (int q2 = 0; q2 < 2; ++q2) {
        lsum[q2] += __shfl_xor(lsum[q2], 16);
        lsum[q2] += __shfl_xor(lsum[q2], 32);
    }

    #pragma unroll
    for (int q2 = 0; q2 < 2; ++q2) {
        #pragma unroll
        for (int r = 0; r < 4; ++r) {
            float inv = 1.0f / __shfl(lsum[q2], (lane & 48) | (quad * 4 + r));
            int c = q0 + wid * 32 + q2 * 16 + quad * 4 + r;
            #pragma unroll
            for (int hb = 0; hb < 4; ++hb) {
                int d = h * 64 + hb * 16 + l15;
                attnb[((size_t)(b * CC + c)) * DD + d] = f2bf(oacc[q2][hb][r] * inv);
            }
        }
    }
}

// ---------------------------------------------------------------------------
extern "C" void kernel_launch(void* const* d_in, const int* in_sizes, int n_in,
                              void* d_out, int out_size, void* d_ws, size_t ws_size,
                              hipStream_t stream)
{
    (void)in_sizes; (void)n_in; (void)out_size; (void)ws_size;
    const float* x      = (const float*)d_in[0];
    const float* w_qkv  = (const float*)d_in[1];
    const float* b_qkv  = (const float*)d_in[2];
    const float* w_proj = (const float*)d_in[3];
    const float* b_proj = (const float*)d_in[4];
    float* out = (float*)d_out;

    ushort* p = (ushort*)d_ws;
    ushort* xbf   = p;  p += (size_t)4 * 1024 * 1024;   // x bf16
    ushort* wqkvT = p;  p += (size_t)3 * 1024 * 1024;   // w_qkv^T bf16
    ushort* wprjT = p;  p += (size_t)1 * 1024 * 1024;   // w_proj^T bf16
    ushort* qbuf  = p;  p += (size_t)4 * 1024 * 1024;   // Q (B,H,C,Hd), pre-scaled
    ushort* kbuf  = p;  p += (size_t)4 * 1024 * 1024;   // K (B,H,C,Hd)
    ushort* vtb   = p;  p += (size_t)4 * 1024 * 1024;   // V^T (B,H,Hd,C)
    ushort* attnb = p;  p += (size_t)4 * 1024 * 1024;   // attention out (B,C,D)

    prep_kernel<<<5120, 256, 0, stream>>>(x, xbf, w_qkv, wqkvT, w_proj, wprjT);

    // QKV: 128x128 tile, 768 blocks (3/CU), 3-ring counted-vmcnt pipeline
    gemm_bt<1, 128><<<dim3(NH3 / 128, (BB * CC) / 128), 256, 0, stream>>>(
        xbf, wqkvT, b_qkv, nullptr, qbuf, kbuf, vtb, BB * CC, NH3, DD);

    attn_mfma7<<<512, 256, 0, stream>>>(qbuf, kbuf, vtb, attnb);

    // proj: M-tile 64 -> 512 blocks (2 blocks/CU), same 3-ring pipeline
    gemm_bt<0, 64><<<dim3(DD / 128, (BB * CC) / 64), 256, 0, stream>>>(
        attnb, wprjT, b_proj, out, nullptr, nullptr, nullptr, BB * CC, DD, DD);
}

// Round 5
// 174.536 us; speedup vs baseline: 1.0244x; 1.0244x over previous
//
#include <hip/hip_runtime.h>
#include <cstdint>

#define BB 4
#define CC 1024
#define DD 1024
#define HH 16
#define HD 64
#define NH3 3072

typedef __attribute__((ext_vector_type(8))) short short8;   // 8 x bf16 (4 VGPRs)
typedef __attribute__((ext_vector_type(4))) float f32x4;

#define MFMA16(a, b, c) __builtin_amdgcn_mfma_f32_16x16x32_bf16(a, b, c, 0, 0, 0)
#define EXP2 __builtin_amdgcn_exp2f

// async global->LDS, 16B per lane; LDS dest = uniform base + lane*16
__device__ __forceinline__ void glds16(const void* g, void* l) {
    __builtin_amdgcn_global_load_lds(
        (const __attribute__((address_space(1))) void*)g,
        (__attribute__((address_space(3))) void*)l, 16, 0, 0);
}

__device__ __forceinline__ ushort f2bf(float f) {
    union { float f; uint32_t u; } v; v.f = f;
    uint32_t r = v.u + 0x7FFF + ((v.u >> 16) & 1);   // round-to-nearest-even
    return (ushort)(r >> 16);
}

// pack two fp32 -> bf16x2 via v_perm_b32
__device__ __forceinline__ uint32_t pack2bf(float a, float b) {
    uint32_t ua = __float_as_uint(a), ub = __float_as_uint(b);
    ua += 0x7FFF + ((ua >> 16) & 1);
    ub += 0x7FFF + ((ub >> 16) & 1);
    return __builtin_amdgcn_perm(ua, ub, 0x03020706);  // lo16=bf(a), hi16=bf(b)
}

// ---------------------------------------------------------------------------
// prep: fused x->bf16 convert + w_qkv^T + w_proj^T (one launch)
// ---------------------------------------------------------------------------
__global__ __launch_bounds__(256)
void prep_kernel(const float* __restrict__ x, ushort* __restrict__ xbf,
                 const float* __restrict__ wqkv, ushort* __restrict__ wqkvT,
                 const float* __restrict__ wprj, ushort* __restrict__ wprjT)
{
    __shared__ float Ts[64 * 65];
    const int blk = blockIdx.x;
    const int t = threadIdx.x;

    if (blk < 4096) {
        int i = blk * 256 + t;
        float4 v = ((const float4*)x)[i];
        ushort4 o;
        o.x = f2bf(v.x); o.y = f2bf(v.y); o.z = f2bf(v.z); o.w = f2bf(v.w);
        ((ushort4*)xbf)[i] = o;
        return;
    }

    const float* in; ushort* outp; int K, N, n0, k0;
    if (blk < 4864) {
        int bx = blk - 4096;
        in = wqkv; outp = wqkvT; K = DD; N = NH3;
        n0 = (bx % 48) * 64; k0 = (bx / 48) * 64;
    } else {
        int bx = blk - 4864;
        in = wprj; outp = wprjT; K = DD; N = DD;
        n0 = (bx % 16) * 64; k0 = (bx / 16) * 64;
    }
    #pragma unroll
    for (int i = 0; i < 16; ++i) {
        int idx = t + i * 256;
        int r = idx >> 6, c = idx & 63;
        Ts[r * 65 + c] = in[(size_t)(k0 + r) * N + n0 + c];
    }
    __syncthreads();
    #pragma unroll
    for (int i = 0; i < 16; ++i) {
        int idx = t + i * 256;
        int rr = idx >> 6, cc = idx & 63;
        outp[(size_t)(n0 + rr) * K + k0 + cc] = f2bf(Ts[cc * 65 + rr]);
    }
}

// ---------------------------------------------------------------------------
// bf16 MFMA GEMM: MT x 128 tile, BK=32, 3-deep LDS ring + COUNTED vmcnt (T4),
// now launched 1D with an XCD-bijective block swizzle (T1): each XCD gets a
// contiguous chunk of the grid -> neighboring tiles share A-panels in its L2.
// MT=128: 4 waves 2x2, wave tile 64x64 (4x4 MFMA), L=4, LDS 48KB (3 blk/CU).
// MT=64 : 4 waves 2x2, wave tile 32x64 (2x4 MFMA), L=3, LDS 36KB (2 blk/CU).
// MODE 0: fp32 out + bias.  MODE 1: QKV scatter, V transposed.
// ---------------------------------------------------------------------------
template<int MODE, int MT, int SWZ>
__global__ __launch_bounds__(256)
void gemm_bt(const ushort* __restrict__ A, const ushort* __restrict__ Bt,
             const float* __restrict__ bias, float* __restrict__ Cf,
             ushort* __restrict__ qb, ushort* __restrict__ kb, ushort* __restrict__ vtb,
             int M, int N, int K)
{
    constexpr int MI = MT / 32;               // M-dir MFMA tiles per wave
    __shared__ ushort As[3][MT * 32];
    __shared__ ushort Bs[3][128 * 32];

    const int tid = threadIdx.x;
    const int wid = tid >> 6, lane = tid & 63;
    const int quad = lane >> 4, l15 = lane & 15;

    int bxi, byi;
    if (SWZ) {   // grid must be 1D and divisible by 8 (bijective XCD chunking)
        const int flat = blockIdx.x;
        const int cpx = gridDim.x >> 3;
        const int f2 = (flat & 7) * cpx + (flat >> 3);
        const int nbx = N / 128;
        bxi = f2 % nbx; byi = f2 / nbx;
    } else {
        bxi = blockIdx.x; byi = blockIdx.y;
    }
    const int m0 = byi * MT, n0 = bxi * 128;
    const int wm = (wid >> 1) * (MT / 2), wn = (wid & 1) * 64;

    const int sr = lane >> 2;
    const int sc = lane & 3;

    const int ar0 = wid * (MT / 4) + sr;
    const int acg0 = sc ^ ((ar0 >> 1) & 3);
    const int acg1 = sc ^ (((ar0 + 16) >> 1) & 3);
    const ushort* Ar0 = A + (size_t)(m0 + ar0) * K + acg0 * 8;
    const ushort* Ar1 = A + (size_t)(m0 + ar0 + 16) * K + acg1 * 8;   // MT=128 only
    const int br0 = wid * 32 + sr;
    const int bcg0 = sc ^ ((br0 >> 1) & 3);
    const int bcg1 = sc ^ (((br0 + 16) >> 1) & 3);
    const ushort* Br0 = Bt + (size_t)(n0 + br0) * K + bcg0 * 8;
    const ushort* Br1 = Bt + (size_t)(n0 + br0 + 16) * K + bcg1 * 8;

    f32x4 acc[MI][4];
    #pragma unroll
    for (int i = 0; i < MI; ++i)
        #pragma unroll
        for (int j = 0; j < 4; ++j) acc[i][j] = (f32x4)(0.0f);

#define GSTAGE(kn, bidx) do { \
        glds16(Ar0 + (kn), &As[bidx][(wid * (MT / 4)) * 32]); \
        glds16(Br0 + (kn), &Bs[bidx][(wid * 32) * 32]); \
        if (MT == 128) glds16(Ar1 + (kn), &As[bidx][(wid * 32 + 16) * 32]); \
        glds16(Br1 + (kn), &Bs[bidx][(wid * 32 + 16) * 32]); } while (0)

    GSTAGE(0, 0);
    GSTAGE(32, 1);

    int cur = 0;
    for (int k0 = 0; k0 < K; k0 += 32) {
        if (k0 + 32 < K) {
            if (MT == 128)
                asm volatile("s_waitcnt vmcnt(4)\n\ts_barrier" ::: "memory");
            else
                asm volatile("s_waitcnt vmcnt(3)\n\ts_barrier" ::: "memory");
        } else {
            asm volatile("s_waitcnt vmcnt(0)\n\ts_barrier" ::: "memory");
        }
        if (k0 + 64 < K) {
            const int nb = (cur >= 1) ? cur - 1 : 2;    // (cur+2) % 3
            GSTAGE(k0 + 64, nb);
        }

        short8 af[MI], bf[4];
        #pragma unroll
        for (int i = 0; i < MI; ++i) {
            int row = wm + i * 16 + l15;
            af[i] = *(const short8*)(&As[cur][row * 32 + (quad ^ ((row >> 1) & 3)) * 8]);
        }
        #pragma unroll
        for (int j = 0; j < 4; ++j) {
            int col = wn + j * 16 + l15;
            bf[j] = *(const short8*)(&Bs[cur][col * 32 + (quad ^ ((col >> 1) & 3)) * 8]);
        }
        #pragma unroll
        for (int i = 0; i < MI; ++i)
            #pragma unroll
            for (int j = 0; j < 4; ++j)
                acc[i][j] = MFMA16(af[i], bf[j], acc[i][j]);

        cur = (cur == 2) ? 0 : cur + 1;
    }
#undef GSTAGE

    if (MODE == 0) {
        #pragma unroll
        for (int i = 0; i < MI; ++i) {
            int row = m0 + wm + i * 16 + quad * 4;
            #pragma unroll
            for (int j = 0; j < 4; ++j) {
                int col = n0 + wn + j * 16 + l15;
                float bv = bias[col];
                #pragma unroll
                for (int r = 0; r < 4; ++r)
                    Cf[(size_t)(row + r) * N + col] = acc[i][j][r] + bv;
            }
        }
    } else {
        #pragma unroll
        for (int j = 0; j < 4; ++j) {
            int n = n0 + wn + j * 16 + l15;
            int three = n >> 10;
            int h = (n >> 6) & 15;
            int hd = n & 63;
            float scale = (three == 0) ? 0.1803368801f : 1.0f;  // 0.125*log2(e)
            float bv = bias[n];
            #pragma unroll
            for (int i = 0; i < MI; ++i) {
                int row = m0 + wm + i * 16 + quad * 4;
                #pragma unroll
                for (int r = 0; r < 4; ++r) {
                    int m = row + r;
                    int b = m >> 10, c = m & 1023;
                    ushort val = f2bf((acc[i][j][r] + bv) * scale);
                    if (three == 0)
                        qb[((size_t)((b * HH + h) * CC) + c) * HD + hd] = val;
                    else if (three == 1)
                        kb[((size_t)((b * HH + h) * CC) + c) * HD + hd] = val;
                    else
                        vtb[((size_t)((b * HH + h) * HD) + hd) * CC + c] = val;
                }
            }
        }
    }
}

// ---------------------------------------------------------------------------
// Flash attention v8: v6's cheap wave-private P-in-LDS round-trip (beats the
// v7 shuffle transform on DS-pipe cost) + v7's counted-vmcnt 2-deep K/V ring
// (K tri-buf, V quad-buf -- removes the per-iter vmcnt(0) drain) + setprio
// around the PV MFMA cluster (T5). P is a SINGLE buffer: PV(kt-1) ds_reads
// precede S(kt) ds_writes in program order and the LDS pipe is in-order for
// aliasing addresses, so no double-buffer needed. LDS 74 KB -> 2 blocks/CU.
// ---------------------------------------------------------------------------
__global__ __launch_bounds__(256)
void attn_mfma8(const ushort* __restrict__ qb, const ushort* __restrict__ kb,
                const ushort* __restrict__ vt, ushort* __restrict__ attnb)
{
    __shared__ ushort lds[3 * 4096 + 4 * 4096 + 9216];   // 74 KB
    const uint K0 = 0, K1 = 4096, K2 = 8192;
    const uint V0 = 12288, V1 = 16384, V2 = 20480, V3 = 24576;
    const uint P0 = 28672;                                // single P buffer

    const int tid = threadIdx.x;
    const int wid = tid >> 6, lane = tid & 63;
    const int quad = lane >> 4, l15 = lane & 15;
    const int bh = blockIdx.x & 63;          // bh-fastest: XCD L2 locality
    const int qt = blockIdx.x >> 6;
    const int q0 = qt * 128;
    const int b = bh >> 4, h = bh & 15;

    const ushort* Qp  = qb + ((size_t)bh * CC + q0) * HD;
    const ushort* Kp  = kb + (size_t)bh * CC * HD;
    const ushort* Vtp = vt + (size_t)bh * HD * CC;

    const int sr = lane >> 3;    // 0..7
    const int sc = lane & 7;     // chunk 0..7

    // Q fragments straight from global: B-operand [n=qrow][k=d], kt-invariant
    short8 qf[2][2];
    #pragma unroll
    for (int q2 = 0; q2 < 2; ++q2) {
        int row = wid * 32 + q2 * 16 + l15;
        #pragma unroll
        for (int s = 0; s < 2; ++s)
            qf[q2][s] = *(const short8*)(Qp + (size_t)row * HD + (s * 4 + quad) * 8);
    }

    // staging addresses (kt-invariant parts)
    const int kr = wid * 16 + sr;            // rows kr, kr+8
    const int cgA = sc ^ (kr & 7);
    const int cgB = sc ^ ((kr + 8) & 7);
    const ushort* Kr0 = Kp  + (size_t)kr * HD + cgA * 8;
    const ushort* Kr1 = Kp  + (size_t)(kr + 8) * HD + cgB * 8;
    const ushort* Vr0 = Vtp + (size_t)kr * CC + cgA * 8;
    const ushort* Vr1 = Vtp + (size_t)(kr + 8) * CC + cgB * 8;

    const uint stg0 = (wid * 16) * 64;       // LDS staging offsets within a buffer
    const uint stg1 = (wid * 16 + 8) * 64;

    // prologue: stage tiles 0 and 1 (tile 0 first -- vmcnt counts oldest)
    glds16(Kr0, lds + K0 + stg0);
    glds16(Kr1, lds + K0 + stg1);
    glds16(Vr0, lds + V0 + stg0);
    glds16(Vr1, lds + V0 + stg1);
    glds16(Kr0 + (size_t)64 * HD, lds + K1 + stg0);
    glds16(Kr1 + (size_t)64 * HD, lds + K1 + stg1);
    glds16(Vr0 + 64, lds + V1 + stg0);
    glds16(Vr1 + 64, lds + V1 + stg1);

    f32x4 oacc[2][4];
    #pragma unroll
    for (int q2 = 0; q2 < 2; ++q2)
        #pragma unroll
        for (int hb = 0; hb < 4; ++hb) oacc[q2][hb] = (f32x4)(0.0f);
    float lsum[2] = {0.0f, 0.0f};

    uint ksC = K0, ksN = K1, ksF = K2;
    uint vsP = V3, vsC = V0, vsN = V1, vsF = V2;

    // PV of the previous tile: O += P_prev @ V_prev (vf from vsP, pf from P0)
#define APV() do { \
        short8 vf_[4][2]; \
        _Pragma("unroll") \
        for (int hb = 0; hb < 4; ++hb) { \
            int hr = hb * 16 + l15; \
            vf_[hb][0] = *(const short8*)(lds + vsP + hr * 64 + ((quad ^ (hr & 7)) * 8)); \
            vf_[hb][1] = *(const short8*)(lds + vsP + hr * 64 + (((4 + quad) ^ (hr & 7)) * 8)); \
        } \
        _Pragma("unroll") \
        for (int q2 = 0; q2 < 2; ++q2) { \
            int row = wid * 32 + q2 * 16 + l15; \
            short8 pf0 = *(const short8*)(lds + P0 + row * 72 + quad * 8); \
            short8 pf1 = *(const short8*)(lds + P0 + row * 72 + 32 + quad * 8); \
            __builtin_amdgcn_s_setprio(1); \
            _Pragma("unroll") \
            for (int hb = 0; hb < 4; ++hb) { \
                oacc[q2][hb] = MFMA16(pf0, vf_[hb][0], oacc[q2][hb]); \
                oacc[q2][hb] = MFMA16(pf1, vf_[hb][1], oacc[q2][hb]); \
            } \
            __builtin_amdgcn_s_setprio(0); \
        } \
    } while (0)

    for (int kt = 0; kt < 16; ++kt) {
        // counted wait: tiles <= kt resident; tile kt+1's 4 loads stay in flight
        if (kt < 15) asm volatile("s_waitcnt vmcnt(4)\n\ts_barrier" ::: "memory");
        else         asm volatile("s_waitcnt vmcnt(0)\n\ts_barrier" ::: "memory");

        if (kt < 14) {                        // prefetch tile kt+2 (2-deep)
            const int koff = (kt + 2) * 64;
            glds16(Kr0 + (size_t)koff * HD, lds + ksF + stg0);
            glds16(Kr1 + (size_t)koff * HD, lds + ksF + stg1);
            glds16(Vr0 + koff,              lds + vsF + stg0);
            glds16(Vr1 + koff,              lds + vsF + stg1);
        }

        if (kt > 0) APV();

        // S_kt = K @ Q^T : lane holds S[qrow=l15][key=kb2*16+quad*4+r]
        #pragma unroll
        for (int kb2 = 0; kb2 < 4; ++kb2) {
            int krow = kb2 * 16 + l15;
            short8 kf0 = *(const short8*)(lds + ksC + krow * 64 + ((quad ^ (krow & 7)) * 8));
            short8 kf1 = *(const short8*)(lds + ksC + krow * 64 + (((4 + quad) ^ (krow & 7)) * 8));
            #pragma unroll
            for (int q2 = 0; q2 < 2; ++q2) {
                f32x4 st = (f32x4)(0.0f);
                st = MFMA16(kf0, qf[q2][0], st);
                st = MFMA16(kf1, qf[q2][1], st);
                float p0 = EXP2(st[0]);
                float p1 = EXP2(st[1]);
                float p2 = EXP2(st[2]);
                float p3 = EXP2(st[3]);
                lsum[q2] += (p0 + p1) + (p2 + p3);
                int row = wid * 32 + q2 * 16 + l15;
                *(uint2*)(lds + P0 + row * 72 + kb2 * 16 + quad * 4) =
                    make_uint2(pack2bf(p0, p1), pack2bf(p2, p3));
            }
        }

        // rotate ring buffers
        uint t = ksC; ksC = ksN; ksN = ksF; ksF = t;
        t = vsP; vsP = vsC; vsC = vsN; vsN = vsF; vsF = t;
    }

    // final PV_15: P_15 at P0, V_15 at vsP (post-rotation); wave-private reads
    APV();
#undef APV

    // reduce lsum across the 4 quads (lanes sharing l15)
    #pragma unroll
    for (int q2 = 0; q2 < 2; ++q2) {
        lsum[q2] += __shfl_xor(lsum[q2], 16);
        lsum[q2] += __shfl_xor(lsum[q2], 32);
    }

    #pragma unroll
    for (int q2 = 0; q2 < 2; ++q2) {
        #pragma unroll
        for (int r = 0; r < 4; ++r) {
            float inv = 1.0f / __shfl(lsum[q2], (lane & 48) | (quad * 4 + r));
            int c = q0 + wid * 32 + q2 * 16 + quad * 4 + r;
            #pragma unroll
            for (int hb = 0; hb < 4; ++hb) {
                int d = h * 64 + hb * 16 + l15;
                attnb[((size_t)(b * CC + c)) * DD + d] = f2bf(oacc[q2][hb][r] * inv);
            }
        }
    }
}

// ---------------------------------------------------------------------------
extern "C" void kernel_launch(void* const* d_in, const int* in_sizes, int n_in,
                              void* d_out, int out_size, void* d_ws, size_t ws_size,
                              hipStream_t stream)
{
    (void)in_sizes; (void)n_in; (void)out_size; (void)ws_size;
    const float* x      = (const float*)d_in[0];
    const float* w_qkv  = (const float*)d_in[1];
    const float* b_qkv  = (const float*)d_in[2];
    const float* w_proj = (const float*)d_in[3];
    const float* b_proj = (const float*)d_in[4];
    float* out = (float*)d_out;

    ushort* p = (ushort*)d_ws;
    ushort* xbf   = p;  p += (size_t)4 * 1024 * 1024;   // x bf16
    ushort* wqkvT = p;  p += (size_t)3 * 1024 * 1024;   // w_qkv^T bf16
    ushort* wprjT = p;  p += (size_t)1 * 1024 * 1024;   // w_proj^T bf16
    ushort* qbuf  = p;  p += (size_t)4 * 1024 * 1024;   // Q (B,H,C,Hd), pre-scaled
    ushort* kbuf  = p;  p += (size_t)4 * 1024 * 1024;   // K (B,H,C,Hd)
    ushort* vtb   = p;  p += (size_t)4 * 1024 * 1024;   // V^T (B,H,Hd,C)
    ushort* attnb = p;  p += (size_t)4 * 1024 * 1024;   // attention out (B,C,D)

    prep_kernel<<<5120, 256, 0, stream>>>(x, xbf, w_qkv, wqkvT, w_proj, wprjT);

    // QKV: 128x128 tile, 768 blocks (3/CU), 3-ring counted vmcnt + XCD swizzle
    gemm_bt<1, 128, 1><<<768, 256, 0, stream>>>(
        xbf, wqkvT, b_qkv, nullptr, qbuf, kbuf, vtb, BB * CC, NH3, DD);

    attn_mfma8<<<512, 256, 0, stream>>>(qbuf, kbuf, vtb, attnb);

    // proj: M-tile 64 -> 512 blocks (2 blocks/CU), 3-ring + XCD swizzle
    gemm_bt<0, 64, 1><<<512, 256, 0, stream>>>(
        attnb, wprjT, b_proj, out, nullptr, nullptr, nullptr, BB * CC, DD, DD);
}

// Round 6
// 174.450 us; speedup vs baseline: 1.0249x; 1.0005x over previous
//
#include <hip/hip_runtime.h>
#include <cstdint>

#define BB 4
#define CC 1024
#define DD 1024
#define HH 16
#define HD 64
#define NH3 3072

typedef __attribute__((ext_vector_type(8))) short short8;   // 8 x bf16 (4 VGPRs)
typedef __attribute__((ext_vector_type(4))) float f32x4;

#define MFMA16(a, b, c) __builtin_amdgcn_mfma_f32_16x16x32_bf16(a, b, c, 0, 0, 0)
#define EXP2 __builtin_amdgcn_exp2f

// async global->LDS, 16B per lane; LDS dest = uniform base + lane*16
__device__ __forceinline__ void glds16(const void* g, void* l) {
    __builtin_amdgcn_global_load_lds(
        (const __attribute__((address_space(1))) void*)g,
        (__attribute__((address_space(3))) void*)l, 16, 0, 0);
}

__device__ __forceinline__ ushort f2bf(float f) {
    union { float f; uint32_t u; } v; v.f = f;
    uint32_t r = v.u + 0x7FFF + ((v.u >> 16) & 1);   // round-to-nearest-even
    return (ushort)(r >> 16);
}

// pack two fp32 -> bf16x2 via v_perm_b32
__device__ __forceinline__ uint32_t pack2bf(float a, float b) {
    uint32_t ua = __float_as_uint(a), ub = __float_as_uint(b);
    ua += 0x7FFF + ((ua >> 16) & 1);
    ub += 0x7FFF + ((ub >> 16) & 1);
    return __builtin_amdgcn_perm(ua, ub, 0x03020706);  // lo16=bf(a), hi16=bf(b)
}

// ---------------------------------------------------------------------------
// prep: fused x->bf16 convert + w_qkv^T + w_proj^T (one launch)
// ---------------------------------------------------------------------------
__global__ __launch_bounds__(256)
void prep_kernel(const float* __restrict__ x, ushort* __restrict__ xbf,
                 const float* __restrict__ wqkv, ushort* __restrict__ wqkvT,
                 const float* __restrict__ wprj, ushort* __restrict__ wprjT)
{
    __shared__ float Ts[64 * 65];
    const int blk = blockIdx.x;
    const int t = threadIdx.x;

    if (blk < 4096) {
        int i = blk * 256 + t;
        float4 v = ((const float4*)x)[i];
        ushort4 o;
        o.x = f2bf(v.x); o.y = f2bf(v.y); o.z = f2bf(v.z); o.w = f2bf(v.w);
        ((ushort4*)xbf)[i] = o;
        return;
    }

    const float* in; ushort* outp; int K, N, n0, k0;
    if (blk < 4864) {
        int bx = blk - 4096;
        in = wqkv; outp = wqkvT; K = DD; N = NH3;
        n0 = (bx % 48) * 64; k0 = (bx / 48) * 64;
    } else {
        int bx = blk - 4864;
        in = wprj; outp = wprjT; K = DD; N = DD;
        n0 = (bx % 16) * 64; k0 = (bx / 16) * 64;
    }
    #pragma unroll
    for (int i = 0; i < 16; ++i) {
        int idx = t + i * 256;
        int r = idx >> 6, c = idx & 63;
        Ts[r * 65 + c] = in[(size_t)(k0 + r) * N + n0 + c];
    }
    __syncthreads();
    #pragma unroll
    for (int i = 0; i < 16; ++i) {
        int idx = t + i * 256;
        int rr = idx >> 6, cc = idx & 63;
        outp[(size_t)(n0 + rr) * K + k0 + cc] = f2bf(Ts[cc * 65 + rr]);
    }
}

// ---------------------------------------------------------------------------
// bf16 MFMA GEMM: MT x 128 tile, BK=32, 3-deep LDS ring + COUNTED vmcnt (T4).
// SWZ=1 adds an XCD-bijective 1D block swizzle (T1) -- ONLY valid when the
// per-XCD concurrent working set fits L2 (proj: B = 2 MB < 4 MB). For QKV
// (B = 6 MB) the swizzle thrashed per-XCD L2 and cost +45% (R5 measured:
// 46 -> 67 us, MfmaUtil 21 -> 14%) -- QKV uses the natural 2D x-fastest
// launch, whose round-robin leaves only 3 B-panels resident per XCD.
// MT=128: 4 waves 2x2, wave tile 64x64 (4x4 MFMA), L=4, LDS 48KB (3 blk/CU).
// MT=64 : 4 waves 2x2, wave tile 32x64 (2x4 MFMA), L=3, LDS 36KB (2 blk/CU).
// MODE 0: fp32 out + bias.  MODE 1: QKV scatter, V transposed.
// ---------------------------------------------------------------------------
template<int MODE, int MT, int SWZ>
__global__ __launch_bounds__(256)
void gemm_bt(const ushort* __restrict__ A, const ushort* __restrict__ Bt,
             const float* __restrict__ bias, float* __restrict__ Cf,
             ushort* __restrict__ qb, ushort* __restrict__ kb, ushort* __restrict__ vtb,
             int M, int N, int K)
{
    constexpr int MI = MT / 32;               // M-dir MFMA tiles per wave
    __shared__ ushort As[3][MT * 32];
    __shared__ ushort Bs[3][128 * 32];

    const int tid = threadIdx.x;
    const int wid = tid >> 6, lane = tid & 63;
    const int quad = lane >> 4, l15 = lane & 15;

    int bxi, byi;
    if (SWZ) {   // grid must be 1D and divisible by 8 (bijective XCD chunking)
        const int flat = blockIdx.x;
        const int cpx = gridDim.x >> 3;
        const int f2 = (flat & 7) * cpx + (flat >> 3);
        const int nbx = N / 128;
        bxi = f2 % nbx; byi = f2 / nbx;
    } else {
        bxi = blockIdx.x; byi = blockIdx.y;
    }
    const int m0 = byi * MT, n0 = bxi * 128;
    const int wm = (wid >> 1) * (MT / 2), wn = (wid & 1) * 64;

    const int sr = lane >> 2;
    const int sc = lane & 3;

    const int ar0 = wid * (MT / 4) + sr;
    const int acg0 = sc ^ ((ar0 >> 1) & 3);
    const int acg1 = sc ^ (((ar0 + 16) >> 1) & 3);
    const ushort* Ar0 = A + (size_t)(m0 + ar0) * K + acg0 * 8;
    const ushort* Ar1 = A + (size_t)(m0 + ar0 + 16) * K + acg1 * 8;   // MT=128 only
    const int br0 = wid * 32 + sr;
    const int bcg0 = sc ^ ((br0 >> 1) & 3);
    const int bcg1 = sc ^ (((br0 + 16) >> 1) & 3);
    const ushort* Br0 = Bt + (size_t)(n0 + br0) * K + bcg0 * 8;
    const ushort* Br1 = Bt + (size_t)(n0 + br0 + 16) * K + bcg1 * 8;

    f32x4 acc[MI][4];
    #pragma unroll
    for (int i = 0; i < MI; ++i)
        #pragma unroll
        for (int j = 0; j < 4; ++j) acc[i][j] = (f32x4)(0.0f);

#define GSTAGE(kn, bidx) do { \
        glds16(Ar0 + (kn), &As[bidx][(wid * (MT / 4)) * 32]); \
        glds16(Br0 + (kn), &Bs[bidx][(wid * 32) * 32]); \
        if (MT == 128) glds16(Ar1 + (kn), &As[bidx][(wid * 32 + 16) * 32]); \
        glds16(Br1 + (kn), &Bs[bidx][(wid * 32 + 16) * 32]); } while (0)

    GSTAGE(0, 0);
    GSTAGE(32, 1);

    int cur = 0;
    for (int k0 = 0; k0 < K; k0 += 32) {
        if (k0 + 32 < K) {
            if (MT == 128)
                asm volatile("s_waitcnt vmcnt(4)\n\ts_barrier" ::: "memory");
            else
                asm volatile("s_waitcnt vmcnt(3)\n\ts_barrier" ::: "memory");
        } else {
            asm volatile("s_waitcnt vmcnt(0)\n\ts_barrier" ::: "memory");
        }
        if (k0 + 64 < K) {
            const int nb = (cur >= 1) ? cur - 1 : 2;    // (cur+2) % 3
            GSTAGE(k0 + 64, nb);
        }

        short8 af[MI], bf[4];
        #pragma unroll
        for (int i = 0; i < MI; ++i) {
            int row = wm + i * 16 + l15;
            af[i] = *(const short8*)(&As[cur][row * 32 + (quad ^ ((row >> 1) & 3)) * 8]);
        }
        #pragma unroll
        for (int j = 0; j < 4; ++j) {
            int col = wn + j * 16 + l15;
            bf[j] = *(const short8*)(&Bs[cur][col * 32 + (quad ^ ((col >> 1) & 3)) * 8]);
        }
        #pragma unroll
        for (int i = 0; i < MI; ++i)
            #pragma unroll
            for (int j = 0; j < 4; ++j)
                acc[i][j] = MFMA16(af[i], bf[j], acc[i][j]);

        cur = (cur == 2) ? 0 : cur + 1;
    }
#undef GSTAGE

    if (MODE == 0) {
        #pragma unroll
        for (int i = 0; i < MI; ++i) {
            int row = m0 + wm + i * 16 + quad * 4;
            #pragma unroll
            for (int j = 0; j < 4; ++j) {
                int col = n0 + wn + j * 16 + l15;
                float bv = bias[col];
                #pragma unroll
                for (int r = 0; r < 4; ++r)
                    Cf[(size_t)(row + r) * N + col] = acc[i][j][r] + bv;
            }
        }
    } else {
        #pragma unroll
        for (int j = 0; j < 4; ++j) {
            int n = n0 + wn + j * 16 + l15;
            int three = n >> 10;
            int h = (n >> 6) & 15;
            int hd = n & 63;
            float scale = (three == 0) ? 0.1803368801f : 1.0f;  // 0.125*log2(e)
            float bv = bias[n];
            #pragma unroll
            for (int i = 0; i < MI; ++i) {
                int row = m0 + wm + i * 16 + quad * 4;
                #pragma unroll
                for (int r = 0; r < 4; ++r) {
                    int m = row + r;
                    int b = m >> 10, c = m & 1023;
                    ushort val = f2bf((acc[i][j][r] + bv) * scale);
                    if (three == 0)
                        qb[((size_t)((b * HH + h) * CC) + c) * HD + hd] = val;
                    else if (three == 1)
                        kb[((size_t)((b * HH + h) * CC) + c) * HD + hd] = val;
                    else
                        vtb[((size_t)((b * HH + h) * HD) + hd) * CC + c] = val;
                }
            }
        }
    }
}

// ---------------------------------------------------------------------------
// Flash attention v8: v6's cheap wave-private P-in-LDS round-trip (beats the
// v7 shuffle transform on DS-pipe cost) + v7's counted-vmcnt 2-deep K/V ring
// (K tri-buf, V quad-buf -- removes the per-iter vmcnt(0) drain) + setprio
// around the PV MFMA cluster (T5). P is a SINGLE buffer: PV(kt-1) ds_reads
// precede S(kt) ds_writes in program order and the LDS pipe is in-order for
// aliasing addresses, so no double-buffer needed. LDS 74 KB -> 2 blocks/CU.
// (unchanged from R5 -- part of the working 107 us remainder)
// ---------------------------------------------------------------------------
__global__ __launch_bounds__(256)
void attn_mfma8(const ushort* __restrict__ qb, const ushort* __restrict__ kb,
                const ushort* __restrict__ vt, ushort* __restrict__ attnb)
{
    __shared__ ushort lds[3 * 4096 + 4 * 4096 + 9216];   // 74 KB
    const uint K0 = 0, K1 = 4096, K2 = 8192;
    const uint V0 = 12288, V1 = 16384, V2 = 20480, V3 = 24576;
    const uint P0 = 28672;                                // single P buffer

    const int tid = threadIdx.x;
    const int wid = tid >> 6, lane = tid & 63;
    const int quad = lane >> 4, l15 = lane & 15;
    const int bh = blockIdx.x & 63;          // bh-fastest: XCD L2 locality
    const int qt = blockIdx.x >> 6;
    const int q0 = qt * 128;
    const int b = bh >> 4, h = bh & 15;

    const ushort* Qp  = qb + ((size_t)bh * CC + q0) * HD;
    const ushort* Kp  = kb + (size_t)bh * CC * HD;
    const ushort* Vtp = vt + (size_t)bh * HD * CC;

    const int sr = lane >> 3;    // 0..7
    const int sc = lane & 7;     // chunk 0..7

    // Q fragments straight from global: B-operand [n=qrow][k=d], kt-invariant
    short8 qf[2][2];
    #pragma unroll
    for (int q2 = 0; q2 < 2; ++q2) {
        int row = wid * 32 + q2 * 16 + l15;
        #pragma unroll
        for (int s = 0; s < 2; ++s)
            qf[q2][s] = *(const short8*)(Qp + (size_t)row * HD + (s * 4 + quad) * 8);
    }

    // staging addresses (kt-invariant parts)
    const int kr = wid * 16 + sr;            // rows kr, kr+8
    const int cgA = sc ^ (kr & 7);
    const int cgB = sc ^ ((kr + 8) & 7);
    const ushort* Kr0 = Kp  + (size_t)kr * HD + cgA * 8;
    const ushort* Kr1 = Kp  + (size_t)(kr + 8) * HD + cgB * 8;
    const ushort* Vr0 = Vtp + (size_t)kr * CC + cgA * 8;
    const ushort* Vr1 = Vtp + (size_t)(kr + 8) * CC + cgB * 8;

    const uint stg0 = (wid * 16) * 64;       // LDS staging offsets within a buffer
    const uint stg1 = (wid * 16 + 8) * 64;

    // prologue: stage tiles 0 and 1 (tile 0 first -- vmcnt counts oldest)
    glds16(Kr0, lds + K0 + stg0);
    glds16(Kr1, lds + K0 + stg1);
    glds16(Vr0, lds + V0 + stg0);
    glds16(Vr1, lds + V0 + stg1);
    glds16(Kr0 + (size_t)64 * HD, lds + K1 + stg0);
    glds16(Kr1 + (size_t)64 * HD, lds + K1 + stg1);
    glds16(Vr0 + 64, lds + V1 + stg0);
    glds16(Vr1 + 64, lds + V1 + stg1);

    f32x4 oacc[2][4];
    #pragma unroll
    for (int q2 = 0; q2 < 2; ++q2)
        #pragma unroll
        for (int hb = 0; hb < 4; ++hb) oacc[q2][hb] = (f32x4)(0.0f);
    float lsum[2] = {0.0f, 0.0f};

    uint ksC = K0, ksN = K1, ksF = K2;
    uint vsP = V3, vsC = V0, vsN = V1, vsF = V2;

    // PV of the previous tile: O += P_prev @ V_prev (vf from vsP, pf from P0)
#define APV() do { \
        short8 vf_[4][2]; \
        _Pragma("unroll") \
        for (int hb = 0; hb < 4; ++hb) { \
            int hr = hb * 16 + l15; \
            vf_[hb][0] = *(const short8*)(lds + vsP + hr * 64 + ((quad ^ (hr & 7)) * 8)); \
            vf_[hb][1] = *(const short8*)(lds + vsP + hr * 64 + (((4 + quad) ^ (hr & 7)) * 8)); \
        } \
        _Pragma("unroll") \
        for (int q2 = 0; q2 < 2; ++q2) { \
            int row = wid * 32 + q2 * 16 + l15; \
            short8 pf0 = *(const short8*)(lds + P0 + row * 72 + quad * 8); \
            short8 pf1 = *(const short8*)(lds + P0 + row * 72 + 32 + quad * 8); \
            __builtin_amdgcn_s_setprio(1); \
            _Pragma("unroll") \
            for (int hb = 0; hb < 4; ++hb) { \
                oacc[q2][hb] = MFMA16(pf0, vf_[hb][0], oacc[q2][hb]); \
                oacc[q2][hb] = MFMA16(pf1, vf_[hb][1], oacc[q2][hb]); \
            } \
            __builtin_amdgcn_s_setprio(0); \
        } \
    } while (0)

    for (int kt = 0; kt < 16; ++kt) {
        // counted wait: tiles <= kt resident; tile kt+1's 4 loads stay in flight
        if (kt < 15) asm volatile("s_waitcnt vmcnt(4)\n\ts_barrier" ::: "memory");
        else         asm volatile("s_waitcnt vmcnt(0)\n\ts_barrier" ::: "memory");

        if (kt < 14) {                        // prefetch tile kt+2 (2-deep)
            const int koff = (kt + 2) * 64;
            glds16(Kr0 + (size_t)koff * HD, lds + ksF + stg0);
            glds16(Kr1 + (size_t)koff * HD, lds + ksF + stg1);
            glds16(Vr0 + koff,              lds + vsF + stg0);
            glds16(Vr1 + koff,              lds + vsF + stg1);
        }

        if (kt > 0) APV();

        // S_kt = K @ Q^T : lane holds S[qrow=l15][key=kb2*16+quad*4+r]
        #pragma unroll
        for (int kb2 = 0; kb2 < 4; ++kb2) {
            int krow = kb2 * 16 + l15;
            short8 kf0 = *(const short8*)(lds + ksC + krow * 64 + ((quad ^ (krow & 7)) * 8));
            short8 kf1 = *(const short8*)(lds + ksC + krow * 64 + (((4 + quad) ^ (krow & 7)) * 8));
            #pragma unroll
            for (int q2 = 0; q2 < 2; ++q2) {
                f32x4 st = (f32x4)(0.0f);
                st = MFMA16(kf0, qf[q2][0], st);
                st = MFMA16(kf1, qf[q2][1], st);
                float p0 = EXP2(st[0]);
                float p1 = EXP2(st[1]);
                float p2 = EXP2(st[2]);
                float p3 = EXP2(st[3]);
                lsum[q2] += (p0 + p1) + (p2 + p3);
                int row = wid * 32 + q2 * 16 + l15;
                *(uint2*)(lds + P0 + row * 72 + kb2 * 16 + quad * 4) =
                    make_uint2(pack2bf(p0, p1), pack2bf(p2, p3));
            }
        }

        // rotate ring buffers
        uint t = ksC; ksC = ksN; ksN = ksF; ksF = t;
        t = vsP; vsP = vsC; vsC = vsN; vsN = vsF; vsF = t;
    }

    // final PV_15: P_15 at P0, V_15 at vsP (post-rotation); wave-private reads
    APV();
#undef APV

    // reduce lsum across the 4 quads (lanes sharing l15)
    #pragma unroll
    for (int q2 = 0; q2 < 2; ++q2) {
        lsum[q2] += __shfl_xor(lsum[q2], 16);
        lsum[q2] += __shfl_xor(lsum[q2], 32);
    }

    #pragma unroll
    for (int q2 = 0; q2 < 2; ++q2) {
        #pragma unroll
        for (int r = 0; r < 4; ++r) {
            float inv = 1.0f / __shfl(lsum[q2], (lane & 48) | (quad * 4 + r));
            int c = q0 + wid * 32 + q2 * 16 + quad * 4 + r;
            #pragma unroll
            for (int hb = 0; hb < 4; ++hb) {
                int d = h * 64 + hb * 16 + l15;
                attnb[((size_t)(b * CC + c)) * DD + d] = f2bf(oacc[q2][hb][r] * inv);
            }
        }
    }
}

// ---------------------------------------------------------------------------
extern "C" void kernel_launch(void* const* d_in, const int* in_sizes, int n_in,
                              void* d_out, int out_size, void* d_ws, size_t ws_size,
                              hipStream_t stream)
{
    (void)in_sizes; (void)n_in; (void)out_size; (void)ws_size;
    const float* x      = (const float*)d_in[0];
    const float* w_qkv  = (const float*)d_in[1];
    const float* b_qkv  = (const float*)d_in[2];
    const float* w_proj = (const float*)d_in[3];
    const float* b_proj = (const float*)d_in[4];
    float* out = (float*)d_out;

    ushort* p = (ushort*)d_ws;
    ushort* xbf   = p;  p += (size_t)4 * 1024 * 1024;   // x bf16
    ushort* wqkvT = p;  p += (size_t)3 * 1024 * 1024;   // w_qkv^T bf16
    ushort* wprjT = p;  p += (size_t)1 * 1024 * 1024;   // w_proj^T bf16
    ushort* qbuf  = p;  p += (size_t)4 * 1024 * 1024;   // Q (B,H,C,Hd), pre-scaled
    ushort* kbuf  = p;  p += (size_t)4 * 1024 * 1024;   // K (B,H,C,Hd)
    ushort* vtb   = p;  p += (size_t)4 * 1024 * 1024;   // V^T (B,H,Hd,C)
    ushort* attnb = p;  p += (size_t)4 * 1024 * 1024;   // attention out (B,C,D)

    prep_kernel<<<5120, 256, 0, stream>>>(x, xbf, w_qkv, wqkvT, w_proj, wprjT);

    // QKV: 128x128 tile, 2D x-fastest launch (NO swizzle -- R5 showed the
    // chunked swizzle thrashes per-XCD L2 when B = 6 MB; natural round-robin
    // keeps only 3 B-panels per XCD). 768 blocks (3/CU), 3-ring counted vmcnt.
    gemm_bt<1, 128, 0><<<dim3(NH3 / 128, (BB * CC) / 128), 256, 0, stream>>>(
        xbf, wqkvT, b_qkv, nullptr, qbuf, kbuf, vtb, BB * CC, NH3, DD);

    attn_mfma8<<<512, 256, 0, stream>>>(qbuf, kbuf, vtb, attnb);

    // proj: M-tile 64 -> 512 blocks (2 blocks/CU), 3-ring + XCD swizzle
    // (B = 2 MB fits per-XCD L2 -- swizzle mechanism-safe here)
    gemm_bt<0, 64, 1><<<512, 256, 0, stream>>>(
        attnb, wprjT, b_proj, out, nullptr, nullptr, nullptr, BB * CC, DD, DD);
}

// Round 7
// 171.976 us; speedup vs baseline: 1.0396x; 1.0144x over previous
//
#include <hip/hip_runtime.h>
#include <cstdint>

#define BB 4
#define CC 1024
#define DD 1024
#define HH 16
#define HD 64
#define NH3 3072

typedef __attribute__((ext_vector_type(8))) short short8;   // 8 x bf16 (4 VGPRs)
typedef __attribute__((ext_vector_type(4))) float f32x4;
typedef __attribute__((ext_vector_type(16))) float f32x16;

#define MFMA16(a, b, c) __builtin_amdgcn_mfma_f32_16x16x32_bf16(a, b, c, 0, 0, 0)
#define MFMA32(a, b, c) __builtin_amdgcn_mfma_f32_32x32x16_bf16(a, b, c, 0, 0, 0)
#define EXP2 __builtin_amdgcn_exp2f

// async global->LDS, 16B per lane; LDS dest = uniform base + lane*16
__device__ __forceinline__ void glds16(const void* g, void* l) {
    __builtin_amdgcn_global_load_lds(
        (const __attribute__((address_space(1))) void*)g,
        (__attribute__((address_space(3))) void*)l, 16, 0, 0);
}

__device__ __forceinline__ ushort f2bf(float f) {
    union { float f; uint32_t u; } v; v.f = f;
    uint32_t r = v.u + 0x7FFF + ((v.u >> 16) & 1);   // round-to-nearest-even
    return (ushort)(r >> 16);
}

// pack two fp32 -> bf16x2 via v_perm_b32
__device__ __forceinline__ uint32_t pack2bf(float a, float b) {
    uint32_t ua = __float_as_uint(a), ub = __float_as_uint(b);
    ua += 0x7FFF + ((ua >> 16) & 1);
    ub += 0x7FFF + ((ub >> 16) & 1);
    return __builtin_amdgcn_perm(ua, ub, 0x03020706);  // lo16=bf(a), hi16=bf(b)
}

// ---------------------------------------------------------------------------
// prep: fused x->bf16 convert + w_qkv^T + w_proj^T (one launch)
// ---------------------------------------------------------------------------
__global__ __launch_bounds__(256)
void prep_kernel(const float* __restrict__ x, ushort* __restrict__ xbf,
                 const float* __restrict__ wqkv, ushort* __restrict__ wqkvT,
                 const float* __restrict__ wprj, ushort* __restrict__ wprjT)
{
    __shared__ float Ts[64 * 65];
    const int blk = blockIdx.x;
    const int t = threadIdx.x;

    if (blk < 4096) {
        int i = blk * 256 + t;
        float4 v = ((const float4*)x)[i];
        ushort4 o;
        o.x = f2bf(v.x); o.y = f2bf(v.y); o.z = f2bf(v.z); o.w = f2bf(v.w);
        ((ushort4*)xbf)[i] = o;
        return;
    }

    const float* in; ushort* outp; int K, N, n0, k0;
    if (blk < 4864) {
        int bx = blk - 4096;
        in = wqkv; outp = wqkvT; K = DD; N = NH3;
        n0 = (bx % 48) * 64; k0 = (bx / 48) * 64;
    } else {
        int bx = blk - 4864;
        in = wprj; outp = wprjT; K = DD; N = DD;
        n0 = (bx % 16) * 64; k0 = (bx / 16) * 64;
    }
    #pragma unroll
    for (int i = 0; i < 16; ++i) {
        int idx = t + i * 256;
        int r = idx >> 6, c = idx & 63;
        Ts[r * 65 + c] = in[(size_t)(k0 + r) * N + n0 + c];
    }
    __syncthreads();
    #pragma unroll
    for (int i = 0; i < 16; ++i) {
        int idx = t + i * 256;
        int rr = idx >> 6, cc = idx & 63;
        outp[(size_t)(n0 + rr) * K + k0 + cc] = f2bf(Ts[cc * 65 + rr]);
    }
}

// ---------------------------------------------------------------------------
// bf16 MFMA GEMM: MT x 128 tile, BK=32, 3-deep LDS ring + COUNTED vmcnt (T4).
// SWZ=1: XCD-bijective swizzle -- only when per-XCD working set fits L2
// (proj yes, QKV no; R5 measured the QKV case at +45%).
// (unchanged from R6 -- attribution anchor)
// ---------------------------------------------------------------------------
template<int MODE, int MT, int SWZ>
__global__ __launch_bounds__(256)
void gemm_bt(const ushort* __restrict__ A, const ushort* __restrict__ Bt,
             const float* __restrict__ bias, float* __restrict__ Cf,
             ushort* __restrict__ qb, ushort* __restrict__ kb, ushort* __restrict__ vtb,
             int M, int N, int K)
{
    constexpr int MI = MT / 32;               // M-dir MFMA tiles per wave
    __shared__ ushort As[3][MT * 32];
    __shared__ ushort Bs[3][128 * 32];

    const int tid = threadIdx.x;
    const int wid = tid >> 6, lane = tid & 63;
    const int quad = lane >> 4, l15 = lane & 15;

    int bxi, byi;
    if (SWZ) {   // grid must be 1D and divisible by 8 (bijective XCD chunking)
        const int flat = blockIdx.x;
        const int cpx = gridDim.x >> 3;
        const int f2 = (flat & 7) * cpx + (flat >> 3);
        const int nbx = N / 128;
        bxi = f2 % nbx; byi = f2 / nbx;
    } else {
        bxi = blockIdx.x; byi = blockIdx.y;
    }
    const int m0 = byi * MT, n0 = bxi * 128;
    const int wm = (wid >> 1) * (MT / 2), wn = (wid & 1) * 64;

    const int sr = lane >> 2;
    const int sc = lane & 3;

    const int ar0 = wid * (MT / 4) + sr;
    const int acg0 = sc ^ ((ar0 >> 1) & 3);
    const int acg1 = sc ^ (((ar0 + 16) >> 1) & 3);
    const ushort* Ar0 = A + (size_t)(m0 + ar0) * K + acg0 * 8;
    const ushort* Ar1 = A + (size_t)(m0 + ar0 + 16) * K + acg1 * 8;   // MT=128 only
    const int br0 = wid * 32 + sr;
    const int bcg0 = sc ^ ((br0 >> 1) & 3);
    const int bcg1 = sc ^ (((br0 + 16) >> 1) & 3);
    const ushort* Br0 = Bt + (size_t)(n0 + br0) * K + bcg0 * 8;
    const ushort* Br1 = Bt + (size_t)(n0 + br0 + 16) * K + bcg1 * 8;

    f32x4 acc[MI][4];
    #pragma unroll
    for (int i = 0; i < MI; ++i)
        #pragma unroll
        for (int j = 0; j < 4; ++j) acc[i][j] = (f32x4)(0.0f);

#define GSTAGE(kn, bidx) do { \
        glds16(Ar0 + (kn), &As[bidx][(wid * (MT / 4)) * 32]); \
        glds16(Br0 + (kn), &Bs[bidx][(wid * 32) * 32]); \
        if (MT == 128) glds16(Ar1 + (kn), &As[bidx][(wid * 32 + 16) * 32]); \
        glds16(Br1 + (kn), &Bs[bidx][(wid * 32 + 16) * 32]); } while (0)

    GSTAGE(0, 0);
    GSTAGE(32, 1);

    int cur = 0;
    for (int k0 = 0; k0 < K; k0 += 32) {
        if (k0 + 32 < K) {
            if (MT == 128)
                asm volatile("s_waitcnt vmcnt(4)\n\ts_barrier" ::: "memory");
            else
                asm volatile("s_waitcnt vmcnt(3)\n\ts_barrier" ::: "memory");
        } else {
            asm volatile("s_waitcnt vmcnt(0)\n\ts_barrier" ::: "memory");
        }
        if (k0 + 64 < K) {
            const int nb = (cur >= 1) ? cur - 1 : 2;    // (cur+2) % 3
            GSTAGE(k0 + 64, nb);
        }

        short8 af[MI], bf[4];
        #pragma unroll
        for (int i = 0; i < MI; ++i) {
            int row = wm + i * 16 + l15;
            af[i] = *(const short8*)(&As[cur][row * 32 + (quad ^ ((row >> 1) & 3)) * 8]);
        }
        #pragma unroll
        for (int j = 0; j < 4; ++j) {
            int col = wn + j * 16 + l15;
            bf[j] = *(const short8*)(&Bs[cur][col * 32 + (quad ^ ((col >> 1) & 3)) * 8]);
        }
        #pragma unroll
        for (int i = 0; i < MI; ++i)
            #pragma unroll
            for (int j = 0; j < 4; ++j)
                acc[i][j] = MFMA16(af[i], bf[j], acc[i][j]);

        cur = (cur == 2) ? 0 : cur + 1;
    }
#undef GSTAGE

    if (MODE == 0) {
        #pragma unroll
        for (int i = 0; i < MI; ++i) {
            int row = m0 + wm + i * 16 + quad * 4;
            #pragma unroll
            for (int j = 0; j < 4; ++j) {
                int col = n0 + wn + j * 16 + l15;
                float bv = bias[col];
                #pragma unroll
                for (int r = 0; r < 4; ++r)
                    Cf[(size_t)(row + r) * N + col] = acc[i][j][r] + bv;
            }
        }
    } else {
        #pragma unroll
        for (int j = 0; j < 4; ++j) {
            int n = n0 + wn + j * 16 + l15;
            int three = n >> 10;
            int h = (n >> 6) & 15;
            int hd = n & 63;
            float scale = (three == 0) ? 0.1803368801f : 1.0f;  // 0.125*log2(e)
            float bv = bias[n];
            #pragma unroll
            for (int i = 0; i < MI; ++i) {
                int row = m0 + wm + i * 16 + quad * 4;
                #pragma unroll
                for (int r = 0; r < 4; ++r) {
                    int m = row + r;
                    int b = m >> 10, c = m & 1023;
                    ushort val = f2bf((acc[i][j][r] + bv) * scale);
                    if (three == 0)
                        qb[((size_t)((b * HH + h) * CC) + c) * HD + hd] = val;
                    else if (three == 1)
                        kb[((size_t)((b * HH + h) * CC) + c) * HD + hd] = val;
                    else
                        vtb[((size_t)((b * HH + h) * HD) + hd) * CC + c] = val;
                }
            }
        }
    }
}

// ---------------------------------------------------------------------------
// Flash attention v9: 32x32x16 MFMA + P fully in registers.
// S = K·Q^T via mfma_32x32x16: lane's col (lane&31) = its q-row, so the
// whole P row-slice stays lane-local. exp+pack2bf as before; the PV A-frag
// halves are exchanged with v_permlane32_swap_b32 (one swap produces BOTH
// output dwords: new_x = d0/d1 lane<32 own : partner's group, new_y = d2/d3).
// Removes the 18 KB P LDS buffer (74 -> 56 KB) and its ds round-trip;
// halves MFMA instruction count (16 vs 32 per wave per K-tile).
// Staging / K3+V4 ring / counted vmcnt(4) / barriers: byte-identical to v8.
//
// Layout derivation (verified element-wise):
//  S D-layout: col=lane&31 -> q, row=(reg&3)+8*(reg>>2)+4*(lane>>5) -> key.
//  Lane's packed pk[kb][2g+j'] = keys {8g+4*hi+2j', +1} of q=lane&31.
//  PV A-frag (k-step m, kb=m>>1, sub=m&1) needs keys m*16+hi*8+{0..7}:
//  x=pk[kb][4*sub+j'], y=pk[kb][4*sub+2+j']; after permlane32_swap(x,y):
//  x = keys lo-octet (own for hi=0, partner for hi=1), y = hi-octet. q.e.d.
// ---------------------------------------------------------------------------
__global__ __launch_bounds__(256)
void attn_mfma9(const ushort* __restrict__ qb, const ushort* __restrict__ kbuf,
                const ushort* __restrict__ vt, ushort* __restrict__ attnb)
{
    __shared__ ushort lds[3 * 4096 + 4 * 4096];   // 56 KB: K tri-buf + V quad-buf
    const uint K0 = 0, K1 = 4096, K2 = 8192;
    const uint V0 = 12288, V1 = 16384, V2 = 20480, V3 = 24576;

    const int tid = threadIdx.x;
    const int wid = tid >> 6, lane = tid & 63;
    const int l31 = lane & 31, hi = lane >> 5;
    const int bh = blockIdx.x & 63;          // bh-fastest: XCD L2 locality
    const int qt = blockIdx.x >> 6;
    const int q0 = qt * 128;
    const int b = bh >> 4, h = bh & 15;

    const ushort* Qp  = qb  + ((size_t)bh * CC + q0) * HD;
    const ushort* Kp  = kbuf + (size_t)bh * CC * HD;
    const ushort* Vtp = vt  + (size_t)bh * HD * CC;

    // Q fragments FIRST (4 x 16B) -- their vmcnt slots are the 4 oldest, so
    // the loop-top vmcnt(4) drains {qf, tile-0} exactly as in v8.
    // B-operand [k=d][col=q]: lane: q = wid*32+l31, d-elems = s*16 + hi*8.
    short8 qf[4];
    {
        const int qrow = wid * 32 + l31;
        #pragma unroll
        for (int s = 0; s < 4; ++s)
            qf[s] = *(const short8*)(Qp + (size_t)qrow * HD + s * 16 + hi * 8);
    }

    // staging addresses (identical to v8)
    const int sr = lane >> 3;    // 0..7
    const int sc = lane & 7;     // chunk 0..7
    const int kr = wid * 16 + sr;            // rows kr, kr+8
    const int cgA = sc ^ (kr & 7);
    const int cgB = sc ^ ((kr + 8) & 7);
    const ushort* Kr0 = Kp  + (size_t)kr * HD + cgA * 8;
    const ushort* Kr1 = Kp  + (size_t)(kr + 8) * HD + cgB * 8;
    const ushort* Vr0 = Vtp + (size_t)kr * CC + cgA * 8;
    const ushort* Vr1 = Vtp + (size_t)(kr + 8) * CC + cgB * 8;

    const uint stg0 = (wid * 16) * 64;
    const uint stg1 = (wid * 16 + 8) * 64;

    // prologue: stage tiles 0 and 1 (tile 0 first -- vmcnt counts oldest)
    glds16(Kr0, lds + K0 + stg0);
    glds16(Kr1, lds + K0 + stg1);
    glds16(Vr0, lds + V0 + stg0);
    glds16(Vr1, lds + V0 + stg1);
    glds16(Kr0 + (size_t)64 * HD, lds + K1 + stg0);
    glds16(Kr1 + (size_t)64 * HD, lds + K1 + stg1);
    glds16(Vr0 + 64, lds + V1 + stg0);
    glds16(Vr1 + 64, lds + V1 + stg1);

    f32x16 oacc[2];
    oacc[0] = (f32x16)(0.0f);
    oacc[1] = (f32x16)(0.0f);
    float lsum = 0.0f;

    uint ksC = K0, ksN = K1, ksF = K2;
    uint vsP = V3, vsC = V0, vsN = V1, vsF = V2;

    uint32_t pkA[2][8], pkB[2][8];

    // PV of the PREVIOUS tile: O += P_prev @ V_prev (V from vsP, P from PKP)
#define APV9(PKP) do { \
        __builtin_amdgcn_s_setprio(1); \
        _Pragma("unroll") \
        for (int m = 0; m < 4; ++m) { \
            const int kb2_ = m >> 1, s4_ = (m & 1) * 4; \
            uint32_t x0_ = PKP[kb2_][s4_ + 0], x1_ = PKP[kb2_][s4_ + 1]; \
            uint32_t y0_ = PKP[kb2_][s4_ + 2], y1_ = PKP[kb2_][s4_ + 3]; \
            asm("v_permlane32_swap_b32 %0, %1" : "+v"(x0_), "+v"(y0_)); \
            asm("v_permlane32_swap_b32 %0, %1" : "+v"(x1_), "+v"(y1_)); \
            union { short8 s; uint32_t u[4]; } pu_; \
            pu_.u[0] = x0_; pu_.u[1] = x1_; pu_.u[2] = y0_; pu_.u[3] = y1_; \
            _Pragma("unroll") \
            for (int db_ = 0; db_ < 2; ++db_) { \
                int hr_ = db_ * 32 + l31; \
                short8 vf_ = *(const short8*)(lds + vsP + hr_ * 64 + \
                                (((m * 2 + hi) ^ (hr_ & 7)) * 8)); \
                oacc[db_] = MFMA32(pu_.s, vf_, oacc[db_]); \
            } \
        } \
        __builtin_amdgcn_s_setprio(0); \
    } while (0)

#define AITER9(kt, PKP, PKC) do { \
        if ((kt) < 15) asm volatile("s_waitcnt vmcnt(4)\n\ts_barrier" ::: "memory"); \
        else           asm volatile("s_waitcnt vmcnt(0)\n\ts_barrier" ::: "memory"); \
        if ((kt) < 14) {                     /* prefetch tile kt+2 (2-deep) */ \
            const int koff_ = ((kt) + 2) * 64; \
            glds16(Kr0 + (size_t)koff_ * HD, lds + ksF + stg0); \
            glds16(Kr1 + (size_t)koff_ * HD, lds + ksF + stg1); \
            glds16(Vr0 + koff_,              lds + vsF + stg0); \
            glds16(Vr1 + koff_,              lds + vsF + stg1); \
        } \
        if ((kt) > 0) { APV9(PKP); } \
        /* S_kt: D[key][q], lane col = q = wid*32+l31 */ \
        _Pragma("unroll") \
        for (int kb2 = 0; kb2 < 2; ++kb2) { \
            f32x16 sacc = (f32x16)(0.0f); \
            _Pragma("unroll") \
            for (int s = 0; s < 4; ++s) { \
                int row = kb2 * 32 + l31; \
                short8 kf = *(const short8*)(lds + ksC + row * 64 + \
                                (((s * 2 + hi) ^ (row & 7)) * 8)); \
                sacc = MFMA32(kf, qf[s], sacc); \
            } \
            float p_[16]; \
            _Pragma("unroll") \
            for (int r = 0; r < 16; ++r) p_[r] = EXP2(sacc[r]); \
            lsum += ((((p_[0] + p_[1]) + (p_[2] + p_[3])) + \
                      ((p_[4] + p_[5]) + (p_[6] + p_[7]))) + \
                     (((p_[8] + p_[9]) + (p_[10] + p_[11])) + \
                      ((p_[12] + p_[13]) + (p_[14] + p_[15])))); \
            _Pragma("unroll") \
            for (int g = 0; g < 4; ++g) { \
                PKC[kb2][2 * g]     = pack2bf(p_[4 * g],     p_[4 * g + 1]); \
                PKC[kb2][2 * g + 1] = pack2bf(p_[4 * g + 2], p_[4 * g + 3]); \
            } \
        } \
        /* rotate ring buffers (identical to v8) */ \
        uint t_ = ksC; ksC = ksN; ksN = ksF; ksF = t_; \
        t_ = vsP; vsP = vsC; vsC = vsN; vsN = vsF; vsF = t_; \
    } while (0)

    for (int k2 = 0; k2 < 8; ++k2) {        // unroll-by-2: static pkA/pkB swap
        AITER9(2 * k2,     pkA, pkB);
        AITER9(2 * k2 + 1, pkB, pkA);
    }

    // final PV_15: P_15 in pkA, V_15 at vsP (post-rotation)
    APV9(pkA);
#undef AITER9
#undef APV9

    // lsum: lane holds partial for q=l31 over its key-half; combine halves
    lsum += __shfl_xor(lsum, 32);

    // epilogue: lane holds O[q=(r&3)+8*(r>>2)+4*hi + wid*32][d=dblk*32+l31]
    #pragma unroll
    for (int r = 0; r < 16; ++r) {
        int qm = (r & 3) + 8 * (r >> 2) + 4 * hi;     // wave-local q (0..31)
        float inv = 1.0f / __shfl(lsum, qm);          // lanes 0..31 hold lsum[q]
        int c = q0 + wid * 32 + qm;
        #pragma unroll
        for (int dblk = 0; dblk < 2; ++dblk) {
            int d = h * 64 + dblk * 32 + l31;
            attnb[((size_t)(b * CC + c)) * DD + d] = f2bf(oacc[dblk][r] * inv);
        }
    }
}

// ---------------------------------------------------------------------------
extern "C" void kernel_launch(void* const* d_in, const int* in_sizes, int n_in,
                              void* d_out, int out_size, void* d_ws, size_t ws_size,
                              hipStream_t stream)
{
    (void)in_sizes; (void)n_in; (void)out_size; (void)ws_size;
    const float* x      = (const float*)d_in[0];
    const float* w_qkv  = (const float*)d_in[1];
    const float* b_qkv  = (const float*)d_in[2];
    const float* w_proj = (const float*)d_in[3];
    const float* b_proj = (const float*)d_in[4];
    float* out = (float*)d_out;

    ushort* p = (ushort*)d_ws;
    ushort* xbf   = p;  p += (size_t)4 * 1024 * 1024;   // x bf16
    ushort* wqkvT = p;  p += (size_t)3 * 1024 * 1024;   // w_qkv^T bf16
    ushort* wprjT = p;  p += (size_t)1 * 1024 * 1024;   // w_proj^T bf16
    ushort* qbuf  = p;  p += (size_t)4 * 1024 * 1024;   // Q (B,H,C,Hd), pre-scaled
    ushort* kbuf  = p;  p += (size_t)4 * 1024 * 1024;   // K (B,H,C,Hd)
    ushort* vtb   = p;  p += (size_t)4 * 1024 * 1024;   // V^T (B,H,Hd,C)
    ushort* attnb = p;  p += (size_t)4 * 1024 * 1024;   // attention out (B,C,D)

    prep_kernel<<<5120, 256, 0, stream>>>(x, xbf, w_qkv, wqkvT, w_proj, wprjT);

    // QKV: 128x128 tile, 2D x-fastest launch (no swizzle -- R5: B=6MB thrashes
    // per-XCD L2 under chunked swizzle). 768 blocks (3/CU), 3-ring counted vmcnt.
    gemm_bt<1, 128, 0><<<dim3(NH3 / 128, (BB * CC) / 128), 256, 0, stream>>>(
        xbf, wqkvT, b_qkv, nullptr, qbuf, kbuf, vtb, BB * CC, NH3, DD);

    attn_mfma9<<<512, 256, 0, stream>>>(qbuf, kbuf, vtb, attnb);

    // proj: M-tile 64 -> 512 blocks (2 blocks/CU), 3-ring + XCD swizzle
    // (B = 2 MB fits per-XCD L2 -- swizzle mechanism-safe here)
    gemm_bt<0, 64, 1><<<512, 256, 0, stream>>>(
        attnb, wprjT, b_proj, out, nullptr, nullptr, nullptr, BB * CC, DD, DD);
}